// Round 10
// baseline (10011.344 us; speedup 1.0000x reference)
//
#include <hip/hip_runtime.h>
#include <hip/hip_bf16.h>

#define B_   8
#define T_   2048
#define OUT1_OFF 8388608ull   // 8*2048*512

typedef unsigned short u16;
typedef unsigned int   u32;
typedef unsigned long long u64;
typedef __attribute__((ext_vector_type(2))) _Float16 f16x2;

__device__ __forceinline__ u16 f2bf(float f) {
  u32 u = __builtin_bit_cast(u32, f);
  u32 r = (u + 0x7fffu + ((u >> 16) & 1u)) >> 16;   // RNE
  return (u16)r;
}
__device__ __forceinline__ float bf2f(u16 s) {
  u32 u = ((u32)s) << 16;
  return __builtin_bit_cast(float, u);
}
__device__ __forceinline__ u16 f2h(float f) {
  _Float16 h = (_Float16)f;                          // RNE cvt
  return __builtin_bit_cast(u16, h);
}
__device__ __forceinline__ u64 ald64(const u64* p) {
  return __hip_atomic_load(p, __ATOMIC_RELAXED, __HIP_MEMORY_SCOPE_AGENT);
}
__device__ __forceinline__ void ast64(u64* p, u64 v) {
  __hip_atomic_store(p, v, __ATOMIC_RELAXED, __HIP_MEMORY_SCOPE_AGENT);
}
// 2xf16 dot with f32 accumulate (v_dot2_f32_f16), safe fallback
__device__ __forceinline__ float dot2(u32 w, u32 h, float c) {
#if defined(__has_builtin) && __has_builtin(__builtin_amdgcn_fdot2)
  return __builtin_amdgcn_fdot2(__builtin_bit_cast(f16x2, w),
                                __builtin_bit_cast(f16x2, h), c, false);
#else
  f16x2 a = __builtin_bit_cast(f16x2, w), b = __builtin_bit_cast(f16x2, h);
  return c + (float)a.x * (float)b.x + (float)a.y * (float)b.y;
#endif
}

// ---------------------------------------------------------------- init
__global__ void k_init(u64* recs) {
  int i = blockIdx.x * 256 + threadIdx.x;   // 8192 u64 (hrec 4096 + rrec 4096)
  __hip_atomic_store(&recs[i], 0ull, __ATOMIC_RELAXED, __HIP_MEMORY_SCOPE_AGENT);
}

// ---------------------------------------------------------------- weight prep
// WT  (bf16) [3072][1024]: x-part transpose  WT [g*1024+j][k] = W_g[k][j]
// WTh (f16)  [3072][1024]: h-part transpose  WTh[g*1024+j][k] = W_g[1024+k][j]
__global__ __launch_bounds__(256) void k_prep(const float* __restrict__ Wr,
                                              const float* __restrict__ Wu,
                                              const float* __restrict__ Wc,
                                              u16* __restrict__ WT,
                                              u16* __restrict__ WTh) {
  __shared__ float tile[32][33];
  int bid = blockIdx.x;
  int g = bid >> 11;          // 0..2
  int rest = bid & 2047;
  int kt = rest >> 5;         // 0..63  (row tile over 2048)
  int jt = rest & 31;         // 0..31  (col tile over 1024)
  const float* W = (g == 0) ? Wr : ((g == 1) ? Wu : Wc);
  int tid = threadIdx.x;
  int r = tid >> 3, c4 = (tid & 7) * 4;
  const float4 v = *(const float4*)&W[(size_t)(kt * 32 + r) * 1024 + jt * 32 + c4];
  tile[r][c4 + 0] = v.x; tile[r][c4 + 1] = v.y;
  tile[r][c4 + 2] = v.z; tile[r][c4 + 3] = v.w;
  __syncthreads();
  int n = g * 1024 + jt * 32 + r;
  if (kt < 32) {
    int k = kt * 32 + c4;
    ushort4 o;
    o.x = f2bf(tile[c4 + 0][r]); o.y = f2bf(tile[c4 + 1][r]);
    o.z = f2bf(tile[c4 + 2][r]); o.w = f2bf(tile[c4 + 3][r]);
    *(ushort4*)&WT[(size_t)n * 1024 + k] = o;
  } else {
    int k = (kt - 32) * 32 + c4;
    ushort4 o;
    o.x = f2h(tile[c4 + 0][r]); o.y = f2h(tile[c4 + 1][r]);
    o.z = f2h(tile[c4 + 2][r]); o.w = f2h(tile[c4 + 3][r]);
    *(ushort4*)&WTh[(size_t)n * 1024 + k] = o;
  }
}

// ---------------------------------------------------------------- embedding gather -> bf16
__global__ __launch_bounds__(256) void k_gather(const int* __restrict__ tok,
                                                const float* __restrict__ er,
                                                const float* __restrict__ ei,
                                                u16* __restrict__ XS) {
  int row = blockIdx.x * 2 + (threadIdx.x >> 7);  // 0..16383 = b*T+t
  int lt = threadIdx.x & 127;
  int tk = tok[row];
  int c0 = lt * 8;
  const float* p = (c0 < 512) ? (er + (size_t)tk * 512 + c0)
                              : (ei + (size_t)tk * 512 + (c0 - 512));
  float4 v1 = *(const float4*)p;
  float4 v2 = *(const float4*)(p + 4);
  uint4 o;
  o.x = (u32)f2bf(v1.x) | ((u32)f2bf(v1.y) << 16);
  o.y = (u32)f2bf(v1.z) | ((u32)f2bf(v1.w) << 16);
  o.z = (u32)f2bf(v2.x) | ((u32)f2bf(v2.y) << 16);
  o.w = (u32)f2bf(v2.z) | ((u32)f2bf(v2.w) << 16);
  *(uint4*)&XS[(size_t)row * 1024 + c0] = o;
}

// ---------------------------------------------------------------- bf16 MFMA GEMM: XW = XS @ W_top
typedef __attribute__((ext_vector_type(8))) __bf16 bf16x8;
typedef __attribute__((ext_vector_type(4))) float f32x4;

__device__ __forceinline__ void gload16(const void* g, void* l) {
  __builtin_amdgcn_global_load_lds((const __attribute__((address_space(1))) void*)g,
                                   (__attribute__((address_space(3))) void*)l, 16, 0, 0);
}

__global__ __launch_bounds__(256) void k_gemm(const u16* __restrict__ XS,
                                              const u16* __restrict__ WT,
                                              u16* __restrict__ XW) {
  __shared__ u16 As[128 * 32];
  __shared__ u16 Bs[128 * 32];
  int bid = blockIdx.x;
  int m0 = (bid & 127) * 128;   // 128 m-tiles
  int n0 = (bid >> 7) * 128;    // 24 n-tiles
  int tid = threadIdx.x;
  int wave = tid >> 6, lane = tid & 63;
  int wm = wave >> 1, wn = wave & 1;
  f32x4 acc[4][4] = {};
  int lr = lane & 15, lk = (lane >> 4) * 8;
  int srow = lane >> 2, sc8 = (lane & 3) * 8;
  for (int k0 = 0; k0 < 1024; k0 += 32) {
#pragma unroll
    for (int q = 0; q < 2; ++q) {
      int rbase = wave * 32 + q * 16;
      gload16(XS + (size_t)(m0 + rbase + srow) * 1024 + k0 + sc8, &As[rbase * 32]);
      gload16(WT + (size_t)(n0 + rbase + srow) * 1024 + k0 + sc8, &Bs[rbase * 32]);
    }
    __syncthreads();
    bf16x8 a[4], b[4];
#pragma unroll
    for (int mi = 0; mi < 4; ++mi) a[mi] = *(const bf16x8*)&As[(wm * 64 + mi * 16 + lr) * 32 + lk];
#pragma unroll
    for (int ni = 0; ni < 4; ++ni) b[ni] = *(const bf16x8*)&Bs[(wn * 64 + ni * 16 + lr) * 32 + lk];
#pragma unroll
    for (int mi = 0; mi < 4; ++mi)
#pragma unroll
      for (int ni = 0; ni < 4; ++ni)
        acc[mi][ni] = __builtin_amdgcn_mfma_f32_16x16x32_bf16(a[mi], b[ni], acc[mi][ni], 0, 0, 0);
    __syncthreads();
  }
#pragma unroll
  for (int mi = 0; mi < 4; ++mi)
#pragma unroll
    for (int ni = 0; ni < 4; ++ni) {
      int col = n0 + wn * 64 + ni * 16 + lr;
#pragma unroll
      for (int r = 0; r < 4; ++r) {
        int row = m0 + wm * 64 + mi * 16 + (lane >> 4) * 4 + r;
        XW[(size_t)row * 3072 + col] = f2bf(acc[mi][ni][r]);
      }
    }
}

// ---------------------------------------------------------------- wave fold-reduce
// p[N] per lane; returns full-wave dot for index (lane & (N-1)), replicated.
template <int N>
__device__ __forceinline__ float foldreduce(float (&p)[N], int lane) {
#pragma unroll
  for (int s = 0; (1 << s) < N; ++s) {
    const int m = 1 << s;
    const int bit = (lane >> s) & 1;
#pragma unroll
    for (int i = 0; i < (N >> (s + 1)); ++i) {
      float lo = p[2 * i], hi = p[2 * i + 1];
      float mine = bit ? hi : lo;
      float send = bit ? lo : hi;
      p[i] = mine + __shfl_xor(send, m, 64);
    }
  }
  float v = p[0];
#pragma unroll
  for (int s = 0; s < 6; ++s)
    if ((1 << s) >= N) v += __shfl_xor(v, 1 << s, 64);
  return v;
}

// ---------------------------------------------------------------- persistent GRU
// 8 islands (batch) x 32 WGs x 512 threads (8 waves). WG owns 32 cols; wave w
// owns cols j0+4w..j0+4w+3 for ALL gates (r,u,c) -> u and hown never leave the
// wave. Record q = {tag32 | f16 h[2q], f16 h[2q+1]} (adjacent cols, same-wave
// publisher; consumer k-pairs match one u32 of the f16 weight row -> v_dot2).
// Sync: no barriers; tagged records only (R9-proven). 2 syncthreads/step.
__global__ __launch_bounds__(512, 1) void k_gru(const u16* __restrict__ WTh,
                                                const float* __restrict__ br,
                                                const float* __restrict__ bu,
                                                const float* __restrict__ bc,
                                                const u16* __restrict__ XW,
                                                u64* __restrict__ hrec,
                                                u64* __restrict__ rrec,
                                                float* __restrict__ out) {
  __shared__ u32 h_pk[512];
  __shared__ u32 r_pk[512];

  const int tid = threadIdx.x;
  const int L = tid & 63;
  const int w = tid >> 6;
  const int isl = blockIdx.x >> 5;      // island = batch
  const int wg = blockIdx.x & 31;
  const int j0 = wg * 32;

  // ---- weights into VGPRs (f16-packed pairs, coalesced u32 loads)
  // slot s = gate*4 + i (gate 0=r, 1=u), col j0 + w*4 + i
  u32 wA[8][8];
#pragma unroll
  for (int s = 0; s < 8; ++s) {
    int g = s >> 2, i = s & 3;
    const u32* wr = (const u32*)(WTh + (size_t)(g * 1024 + j0 + w * 4 + i) * 1024);
#pragma unroll
    for (int j2 = 0; j2 < 8; ++j2) wA[s][j2] = wr[64 * j2 + L];
  }
  u32 wB[4][8];
#pragma unroll
  for (int i = 0; i < 4; ++i) {
    const u32* wr = (const u32*)(WTh + (size_t)(2048 + j0 + w * 4 + i) * 1024);
#pragma unroll
    for (int j2 = 0; j2 < 8; ++j2) wB[i][j2] = wr[64 * j2 + L];
  }

  const float biasA = (((L >> 2) & 1) ? bu : br)[j0 + w * 4 + (L & 3)];
  const float bcB = bc[j0 + w * 4 + (L & 3)];
  float hown = 0.f;   // lanes 0-3: h state for col j0+4w+L (fp32 exact)
  float sgA = 0.f;    // lanes 4-7 carry u across phases

  u64* hr = hrec + (size_t)isl * 512;
  u64* rr = rrec + (size_t)isl * 512;
  const int qpub = wg * 16 + w * 2 + ((L >> 1) & 1);   // lanes 0,2 publish

  for (int t = 0; t < T_; ++t) {
    const size_t xrow = ((size_t)isl * T_ + t) * 3072;
    // xw loads in flight during poll
    float xwA = bf2f(XW[xrow + ((L >> 2) & 1) * 1024 + j0 + w * 4 + (L & 3)]);
    float xwB = bf2f(XW[xrow + 2048 + j0 + w * 4 + (L & 3)]);

    // ---- phase A: poll own h record (tag >= t), stage packed payload
    u64 hv = ald64(&hr[tid]);
    while ((u32)(hv >> 32) < (u32)t) hv = ald64(&hr[tid]);
    h_pk[tid] = (u32)hv;
    __syncthreads();

    u32 hq[8];
#pragma unroll
    for (int j2 = 0; j2 < 8; ++j2) hq[j2] = h_pk[64 * j2 + L];
    float acc[8];
#pragma unroll
    for (int s = 0; s < 8; ++s) {
      float a = 0.f;
#pragma unroll
      for (int j2 = 0; j2 < 8; ++j2) a = dot2(wA[s][j2], hq[j2], a);
      acc[s] = a;
    }
    float dA = foldreduce<8>(acc, L);
    sgA = 1.f / (1.f + __expf(-(dA + xwA + biasA)));
    float rh = sgA * hown;                     // meaningful lanes 0-3
    float rhp = __shfl_xor(rh, 1, 64);
    if (L < 4 && (L & 1) == 0) {
      u64 x = ((u64)(u32)(t + 1) << 32) |
              (u64)((u32)f2h(rh) | ((u32)f2h(rhp) << 16));
      ast64(&rr[qpub], x);
    }

    // ---- phase B: poll own rh record (tag >= t+1), stage
    u64 rv = ald64(&rr[tid]);
    while ((u32)(rv >> 32) < (u32)(t + 1)) rv = ald64(&rr[tid]);
    r_pk[tid] = (u32)rv;
    __syncthreads();

    u32 rq[8];
#pragma unroll
    for (int j2 = 0; j2 < 8; ++j2) rq[j2] = r_pk[64 * j2 + L];
    float accB[4];
#pragma unroll
    for (int i = 0; i < 4; ++i) {
      float a = 0.f;
#pragma unroll
      for (int j2 = 0; j2 < 8; ++j2) a = dot2(wB[i][j2], rq[j2], a);
      accB[i] = a;
    }
    float dB = foldreduce<4>(accB, L);
    float pre = dB + xwB + bcB;
    float ax = fabsf(pre);
    float e = __expf(-2.f * ax);
    float cv = copysignf((1.f - e) / (1.f + e), pre);
    float uu = __shfl_xor(sgA, 4, 64);         // lanes 0-3 receive u
    float hn = (1.f - uu) * hown + uu * cv;    // valid lanes 0-3
    if (L < 4) hown = hn;
    float hp = __shfl_xor(hn, 1, 64);
    if (L < 4 && (L & 1) == 0) {
      u64 x = ((u64)(u32)(t + 1) << 32) |
              (u64)((u32)f2h(hn) | ((u32)f2h(hp) << 16));
      ast64(&hr[qpub], x);
    }
    if (L < 4) {
      int j = j0 + w * 4 + L;
      size_t orow = (size_t)isl * T_ + t;
      if (j < 512) out[orow * 512 + j] = hn;
      else out[OUT1_OFF + orow * 512 + (j - 512)] = hn;
    }
  }
}

// ---------------------------------------------------------------- in-place LayerNorm
__global__ __launch_bounds__(256) void k_ln(float* __restrict__ out,
                                            const float* __restrict__ sr,
                                            const float* __restrict__ brr,
                                            const float* __restrict__ si,
                                            const float* __restrict__ bii) {
  int row = blockIdx.x * 4 + (threadIdx.x >> 6);   // 0..32767
  int lane = threadIdx.x & 63;
  float* p = out + (size_t)row * 512;
  float4 v1 = ((const float4*)p)[lane];
  float4 v2 = ((const float4*)p)[64 + lane];
  float s1 = v1.x + v1.y + v1.z + v1.w + v2.x + v2.y + v2.z + v2.w;
  float s2 = v1.x * v1.x + v1.y * v1.y + v1.z * v1.z + v1.w * v1.w +
             v2.x * v2.x + v2.y * v2.y + v2.z * v2.z + v2.w * v2.w;
#pragma unroll
  for (int m = 1; m < 64; m <<= 1) { s1 += __shfl_xor(s1, m, 64); s2 += __shfl_xor(s2, m, 64); }
  float mean = s1 * (1.f / 512.f);
  float var = s2 * (1.f / 512.f) - mean * mean;
  float inv = rsqrtf(var + 1e-6f);
  bool hi2 = row >= 16384;
  const float* sc = hi2 ? si : sr;
  const float* bs = hi2 ? bii : brr;
  float4 g1 = ((const float4*)sc)[lane], g2 = ((const float4*)sc)[64 + lane];
  float4 b1 = ((const float4*)bs)[lane], b2 = ((const float4*)bs)[64 + lane];
  v1.x = (v1.x - mean) * inv * g1.x + b1.x;
  v1.y = (v1.y - mean) * inv * g1.y + b1.y;
  v1.z = (v1.z - mean) * inv * g1.z + b1.z;
  v1.w = (v1.w - mean) * inv * g1.w + b1.w;
  v2.x = (v2.x - mean) * inv * g2.x + b2.x;
  v2.y = (v2.y - mean) * inv * g2.y + b2.y;
  v2.z = (v2.z - mean) * inv * g2.z + b2.z;
  v2.w = (v2.w - mean) * inv * g2.w + b2.w;
  ((float4*)p)[lane] = v1;
  ((float4*)p)[64 + lane] = v2;
}

// ---------------------------------------------------------------- launch
extern "C" void kernel_launch(void* const* d_in, const int* in_sizes, int n_in,
                              void* d_out, int out_size, void* d_ws, size_t ws_size,
                              hipStream_t stream) {
  const int*   tok   = (const int*)d_in[0];
  const float* emb_r = (const float*)d_in[1];
  const float* emb_i = (const float*)d_in[2];
  const float* Wr    = (const float*)d_in[3];
  const float* br    = (const float*)d_in[4];
  const float* Wu    = (const float*)d_in[5];
  const float* bu    = (const float*)d_in[6];
  const float* Wc    = (const float*)d_in[7];
  const float* bc    = (const float*)d_in[8];
  const float* lnrs  = (const float*)d_in[9];
  const float* lnrb  = (const float*)d_in[10];
  const float* lnis  = (const float*)d_in[11];
  const float* lnib  = (const float*)d_in[12];
  float* out = (float*)d_out;
  char* ws = (char*)d_ws;

  u16*   XS    = (u16*)(ws);                       //  33,554,432 B
  u16*   WT    = (u16*)(ws + 33554432);            //   6,291,456 B
  u16*   WTh   = (u16*)(ws + 39845888);            //   6,291,456 B (f16)
  u16*   XW    = (u16*)(ws + 46137344);            // 100,663,296 B
  u64*   hrec  = (u64*)(ws + 146800640);           //      32,768 B (8 isl x 512)
  u64*   rrec  = (u64*)(ws + 146833408);           //      32,768 B

  k_init<<<32, 256, 0, stream>>>(hrec);            // zeroes hrec + rrec (contiguous)
  k_prep<<<6144, 256, 0, stream>>>(Wr, Wu, Wc, WT, WTh);
  k_gather<<<8192, 256, 0, stream>>>(tok, emb_r, emb_i, XS);
  k_gemm<<<3072, 256, 0, stream>>>(XS, WT, XW);
  k_gru<<<256, 512, 0, stream>>>(WTh, br, bu, bc, XW, hrec, rrec, out);
  k_ln<<<8192, 256, 0, stream>>>(out, lnrs, lnrb, lnis, lnib);
}

// Round 11
// 8763.568 us; speedup vs baseline: 1.1424x; 1.1424x over previous
//
#include <hip/hip_runtime.h>
#include <hip/hip_bf16.h>

#define B_   8
#define T_   2048
#define OUT1_OFF 8388608ull   // 8*2048*512

typedef unsigned short u16;
typedef unsigned int   u32;
typedef unsigned long long u64;
typedef __attribute__((ext_vector_type(2))) _Float16 f16x2;

__device__ __forceinline__ u16 f2bf(float f) {
  u32 u = __builtin_bit_cast(u32, f);
  u32 r = (u + 0x7fffu + ((u >> 16) & 1u)) >> 16;   // RNE
  return (u16)r;
}
__device__ __forceinline__ float bf2f(u16 s) {
  u32 u = ((u32)s) << 16;
  return __builtin_bit_cast(float, u);
}
__device__ __forceinline__ u16 f2h(float f) {
  _Float16 h = (_Float16)f;                          // RNE cvt
  return __builtin_bit_cast(u16, h);
}
__device__ __forceinline__ u64 ald64(const u64* p) {
  return __hip_atomic_load(p, __ATOMIC_RELAXED, __HIP_MEMORY_SCOPE_AGENT);
}
__device__ __forceinline__ void ast64(u64* p, u64 v) {
  __hip_atomic_store(p, v, __ATOMIC_RELAXED, __HIP_MEMORY_SCOPE_AGENT);
}
// 2xf16 dot with f32 accumulate (v_dot2_f32_f16), safe fallback
__device__ __forceinline__ float dot2(u32 w, u32 h, float c) {
#if defined(__has_builtin) && __has_builtin(__builtin_amdgcn_fdot2)
  return __builtin_amdgcn_fdot2(__builtin_bit_cast(f16x2, w),
                                __builtin_bit_cast(f16x2, h), c, false);
#else
  f16x2 a = __builtin_bit_cast(f16x2, w), b = __builtin_bit_cast(f16x2, h);
  return c + (float)a.x * (float)b.x + (float)a.y * (float)b.y;
#endif
}

// ---------------------------------------------------------------- init
__global__ void k_init(u64* recs) {
  int i = blockIdx.x * 256 + threadIdx.x;   // 8192 u64 (hrec 4096 + rrec 4096)
  __hip_atomic_store(&recs[i], 0ull, __ATOMIC_RELAXED, __HIP_MEMORY_SCOPE_AGENT);
}

// ---------------------------------------------------------------- weight prep
// WT  (bf16) [3072][1024]: x-part transpose  WT [g*1024+j][k] = W_g[k][j]
// WTh (f16)  [3072][1024]: h-part transpose  WTh[g*1024+j][k] = W_g[1024+k][j]
__global__ __launch_bounds__(256) void k_prep(const float* __restrict__ Wr,
                                              const float* __restrict__ Wu,
                                              const float* __restrict__ Wc,
                                              u16* __restrict__ WT,
                                              u16* __restrict__ WTh) {
  __shared__ float tile[32][33];
  int bid = blockIdx.x;
  int g = bid >> 11;          // 0..2
  int rest = bid & 2047;
  int kt = rest >> 5;         // 0..63  (row tile over 2048)
  int jt = rest & 31;         // 0..31  (col tile over 1024)
  const float* W = (g == 0) ? Wr : ((g == 1) ? Wu : Wc);
  int tid = threadIdx.x;
  int r = tid >> 3, c4 = (tid & 7) * 4;
  const float4 v = *(const float4*)&W[(size_t)(kt * 32 + r) * 1024 + jt * 32 + c4];
  tile[r][c4 + 0] = v.x; tile[r][c4 + 1] = v.y;
  tile[r][c4 + 2] = v.z; tile[r][c4 + 3] = v.w;
  __syncthreads();
  int n = g * 1024 + jt * 32 + r;
  if (kt < 32) {
    int k = kt * 32 + c4;
    ushort4 o;
    o.x = f2bf(tile[c4 + 0][r]); o.y = f2bf(tile[c4 + 1][r]);
    o.z = f2bf(tile[c4 + 2][r]); o.w = f2bf(tile[c4 + 3][r]);
    *(ushort4*)&WT[(size_t)n * 1024 + k] = o;
  } else {
    int k = (kt - 32) * 32 + c4;
    ushort4 o;
    o.x = f2h(tile[c4 + 0][r]); o.y = f2h(tile[c4 + 1][r]);
    o.z = f2h(tile[c4 + 2][r]); o.w = f2h(tile[c4 + 3][r]);
    *(ushort4*)&WTh[(size_t)n * 1024 + k] = o;
  }
}

// ---------------------------------------------------------------- embedding gather -> bf16
__global__ __launch_bounds__(256) void k_gather(const int* __restrict__ tok,
                                                const float* __restrict__ er,
                                                const float* __restrict__ ei,
                                                u16* __restrict__ XS) {
  int row = blockIdx.x * 2 + (threadIdx.x >> 7);  // 0..16383 = b*T+t
  int lt = threadIdx.x & 127;
  int tk = tok[row];
  int c0 = lt * 8;
  const float* p = (c0 < 512) ? (er + (size_t)tk * 512 + c0)
                              : (ei + (size_t)tk * 512 + (c0 - 512));
  float4 v1 = *(const float4*)p;
  float4 v2 = *(const float4*)(p + 4);
  uint4 o;
  o.x = (u32)f2bf(v1.x) | ((u32)f2bf(v1.y) << 16);
  o.y = (u32)f2bf(v1.z) | ((u32)f2bf(v1.w) << 16);
  o.z = (u32)f2bf(v2.x) | ((u32)f2bf(v2.y) << 16);
  o.w = (u32)f2bf(v2.z) | ((u32)f2bf(v2.w) << 16);
  *(uint4*)&XS[(size_t)row * 1024 + c0] = o;
}

// ---------------------------------------------------------------- bf16 MFMA GEMM: XW = XS @ W_top
typedef __attribute__((ext_vector_type(8))) __bf16 bf16x8;
typedef __attribute__((ext_vector_type(4))) float f32x4;

__device__ __forceinline__ void gload16(const void* g, void* l) {
  __builtin_amdgcn_global_load_lds((const __attribute__((address_space(1))) void*)g,
                                   (__attribute__((address_space(3))) void*)l, 16, 0, 0);
}

__global__ __launch_bounds__(256) void k_gemm(const u16* __restrict__ XS,
                                              const u16* __restrict__ WT,
                                              u16* __restrict__ XW) {
  __shared__ u16 As[128 * 32];
  __shared__ u16 Bs[128 * 32];
  int bid = blockIdx.x;
  int m0 = (bid & 127) * 128;   // 128 m-tiles
  int n0 = (bid >> 7) * 128;    // 24 n-tiles
  int tid = threadIdx.x;
  int wave = tid >> 6, lane = tid & 63;
  int wm = wave >> 1, wn = wave & 1;
  f32x4 acc[4][4] = {};
  int lr = lane & 15, lk = (lane >> 4) * 8;
  int srow = lane >> 2, sc8 = (lane & 3) * 8;
  for (int k0 = 0; k0 < 1024; k0 += 32) {
#pragma unroll
    for (int q = 0; q < 2; ++q) {
      int rbase = wave * 32 + q * 16;
      gload16(XS + (size_t)(m0 + rbase + srow) * 1024 + k0 + sc8, &As[rbase * 32]);
      gload16(WT + (size_t)(n0 + rbase + srow) * 1024 + k0 + sc8, &Bs[rbase * 32]);
    }
    __syncthreads();
    bf16x8 a[4], b[4];
#pragma unroll
    for (int mi = 0; mi < 4; ++mi) a[mi] = *(const bf16x8*)&As[(wm * 64 + mi * 16 + lr) * 32 + lk];
#pragma unroll
    for (int ni = 0; ni < 4; ++ni) b[ni] = *(const bf16x8*)&Bs[(wn * 64 + ni * 16 + lr) * 32 + lk];
#pragma unroll
    for (int mi = 0; mi < 4; ++mi)
#pragma unroll
      for (int ni = 0; ni < 4; ++ni)
        acc[mi][ni] = __builtin_amdgcn_mfma_f32_16x16x32_bf16(a[mi], b[ni], acc[mi][ni], 0, 0, 0);
    __syncthreads();
  }
#pragma unroll
  for (int mi = 0; mi < 4; ++mi)
#pragma unroll
    for (int ni = 0; ni < 4; ++ni) {
      int col = n0 + wn * 64 + ni * 16 + lr;
#pragma unroll
      for (int r = 0; r < 4; ++r) {
        int row = m0 + wm * 64 + mi * 16 + (lane >> 4) * 4 + r;
        XW[(size_t)row * 3072 + col] = f2bf(acc[mi][ni][r]);
      }
    }
}

// ---------------------------------------------------------------- wave fold-reduce
// p[N] per lane; returns full-wave dot for index (lane & (N-1)), replicated.
template <int N>
__device__ __forceinline__ float foldreduce(float (&p)[N], int lane) {
#pragma unroll
  for (int s = 0; (1 << s) < N; ++s) {
    const int m = 1 << s;
    const int bit = (lane >> s) & 1;
#pragma unroll
    for (int i = 0; i < (N >> (s + 1)); ++i) {
      float lo = p[2 * i], hi = p[2 * i + 1];
      float mine = bit ? hi : lo;
      float send = bit ? lo : hi;
      p[i] = mine + __shfl_xor(send, m, 64);
    }
  }
  float v = p[0];
#pragma unroll
  for (int s = 0; s < 6; ++s)
    if ((1 << s) >= N) v += __shfl_xor(v, 1 << s, 64);
  return v;
}

// ---------------------------------------------------------------- persistent GRU
// 8 islands (batch) x 32 WGs x 512 threads (8 waves). WG owns 32 cols; wave w
// owns cols j0+4w..j0+4w+3 for ALL gates (r,u,c). Record q = {tag32 | f16
// h[2q], f16 h[2q+1]}. No barriers; tagged records only. 2 syncthreads/step.
// Weights pinned in VGPRs via asm register constraint (R10 lesson: without
// the pin, LLVM sinks the loads into the loop -> L2 reload on critical path).
__global__ __launch_bounds__(512, 1) void k_gru(const u16* __restrict__ WTh,
                                                const float* __restrict__ br,
                                                const float* __restrict__ bu,
                                                const float* __restrict__ bc,
                                                const u16* __restrict__ XW,
                                                u64* __restrict__ hrec,
                                                u64* __restrict__ rrec,
                                                float* __restrict__ out) {
  __shared__ u32 h_pk[512];
  __shared__ u32 r_pk[512];

  const int tid = threadIdx.x;
  const int L = tid & 63;
  const int w = tid >> 6;
  const int isl = blockIdx.x >> 5;      // island = batch
  const int wg = blockIdx.x & 31;
  const int j0 = wg * 32;

  // ---- weights into VGPRs (f16-packed pairs, coalesced u32 loads)
  // slot s = gate*4 + i (gate 0=r, 1=u), col j0 + w*4 + i
  u32 wA[8][8];
#pragma unroll
  for (int s = 0; s < 8; ++s) {
    int g = s >> 2, i = s & 3;
    const u32* wr = (const u32*)(WTh + (size_t)(g * 1024 + j0 + w * 4 + i) * 1024);
#pragma unroll
    for (int j2 = 0; j2 < 8; ++j2) wA[s][j2] = wr[64 * j2 + L];
  }
  u32 wB[4][8];
#pragma unroll
  for (int i = 0; i < 4; ++i) {
    const u32* wr = (const u32*)(WTh + (size_t)(2048 + j0 + w * 4 + i) * 1024);
#pragma unroll
    for (int j2 = 0; j2 < 8; ++j2) wB[i][j2] = wr[64 * j2 + L];
  }
  // pin: force residency, forbid rematerialization inside the loop
#pragma unroll
  for (int s = 0; s < 8; ++s)
#pragma unroll
    for (int j2 = 0; j2 < 8; ++j2) asm volatile("" : "+v"(wA[s][j2]));
#pragma unroll
  for (int i = 0; i < 4; ++i)
#pragma unroll
    for (int j2 = 0; j2 < 8; ++j2) asm volatile("" : "+v"(wB[i][j2]));

  const float biasA = (((L >> 2) & 1) ? bu : br)[j0 + w * 4 + (L & 3)];
  const float bcB = bc[j0 + w * 4 + (L & 3)];
  float hown = 0.f;   // lanes 0-3: h state for col j0+4w+L (fp32 exact)
  float sgA = 0.f;    // lanes 4-7 carry u across phases

  u64* hr = hrec + (size_t)isl * 512;
  u64* rr = rrec + (size_t)isl * 512;
  const int qpub = wg * 16 + w * 2 + ((L >> 1) & 1);   // lanes 0,2 publish

  for (int t = 0; t < T_; ++t) {
    const size_t xrow = ((size_t)isl * T_ + t) * 3072;
    // xw loads in flight during poll (only lanes that use them)
    float xwA = 0.f, xwB = 0.f;
    if (L < 8)
      xwA = bf2f(XW[xrow + ((L >> 2) & 1) * 1024 + j0 + w * 4 + (L & 3)]);
    if (L < 4)
      xwB = bf2f(XW[xrow + 2048 + j0 + w * 4 + (L & 3)]);

    // ---- phase A: poll own h record (tag >= t), stage packed payload
    u64 hv = ald64(&hr[tid]);
    while ((u32)(hv >> 32) < (u32)t) hv = ald64(&hr[tid]);
    h_pk[tid] = (u32)hv;
    __syncthreads();

    u32 hq[8];
#pragma unroll
    for (int j2 = 0; j2 < 8; ++j2) hq[j2] = h_pk[64 * j2 + L];
    float acc[8];
#pragma unroll
    for (int s = 0; s < 8; ++s) {
      float a = 0.f;
#pragma unroll
      for (int j2 = 0; j2 < 8; ++j2) a = dot2(wA[s][j2], hq[j2], a);
      acc[s] = a;
    }
    float dA = foldreduce<8>(acc, L);
    sgA = 1.f / (1.f + __expf(-(dA + xwA + biasA)));
    float rh = sgA * hown;                     // meaningful lanes 0-3
    float rhp = __shfl_xor(rh, 1, 64);
    if (L < 4 && (L & 1) == 0) {
      u64 x = ((u64)(u32)(t + 1) << 32) |
              (u64)((u32)f2h(rh) | ((u32)f2h(rhp) << 16));
      ast64(&rr[qpub], x);
    }

    // ---- phase B: poll own rh record (tag >= t+1), stage
    u64 rv = ald64(&rr[tid]);
    while ((u32)(rv >> 32) < (u32)(t + 1)) rv = ald64(&rr[tid]);
    r_pk[tid] = (u32)rv;
    __syncthreads();

    u32 rq[8];
#pragma unroll
    for (int j2 = 0; j2 < 8; ++j2) rq[j2] = r_pk[64 * j2 + L];
    float accB[4];
#pragma unroll
    for (int i = 0; i < 4; ++i) {
      float a = 0.f;
#pragma unroll
      for (int j2 = 0; j2 < 8; ++j2) a = dot2(wB[i][j2], rq[j2], a);
      accB[i] = a;
    }
    float dB = foldreduce<4>(accB, L);
    float pre = dB + xwB + bcB;
    float ax = fabsf(pre);
    float e = __expf(-2.f * ax);
    float cv = copysignf((1.f - e) / (1.f + e), pre);
    float uu = __shfl_xor(sgA, 4, 64);         // lanes 0-3 receive u
    float hn = (1.f - uu) * hown + uu * cv;    // valid lanes 0-3
    if (L < 4) hown = hn;
    float hp = __shfl_xor(hn, 1, 64);
    if (L < 4 && (L & 1) == 0) {
      u64 x = ((u64)(u32)(t + 1) << 32) |
              (u64)((u32)f2h(hn) | ((u32)f2h(hp) << 16));
      ast64(&hr[qpub], x);
    }
    if (L < 4) {
      int j = j0 + w * 4 + L;
      size_t orow = (size_t)isl * T_ + t;
      if (j < 512) out[orow * 512 + j] = hn;
      else out[OUT1_OFF + orow * 512 + (j - 512)] = hn;
    }
  }
}

// ---------------------------------------------------------------- in-place LayerNorm
__global__ __launch_bounds__(256) void k_ln(float* __restrict__ out,
                                            const float* __restrict__ sr,
                                            const float* __restrict__ brr,
                                            const float* __restrict__ si,
                                            const float* __restrict__ bii) {
  int row = blockIdx.x * 4 + (threadIdx.x >> 6);   // 0..32767
  int lane = threadIdx.x & 63;
  float* p = out + (size_t)row * 512;
  float4 v1 = ((const float4*)p)[lane];
  float4 v2 = ((const float4*)p)[64 + lane];
  float s1 = v1.x + v1.y + v1.z + v1.w + v2.x + v2.y + v2.z + v2.w;
  float s2 = v1.x * v1.x + v1.y * v1.y + v1.z * v1.z + v1.w * v1.w +
             v2.x * v2.x + v2.y * v2.y + v2.z * v2.z + v2.w * v2.w;
#pragma unroll
  for (int m = 1; m < 64; m <<= 1) { s1 += __shfl_xor(s1, m, 64); s2 += __shfl_xor(s2, m, 64); }
  float mean = s1 * (1.f / 512.f);
  float var = s2 * (1.f / 512.f) - mean * mean;
  float inv = rsqrtf(var + 1e-6f);
  bool hi2 = row >= 16384;
  const float* sc = hi2 ? si : sr;
  const float* bs = hi2 ? bii : brr;
  float4 g1 = ((const float4*)sc)[lane], g2 = ((const float4*)sc)[64 + lane];
  float4 b1 = ((const float4*)bs)[lane], b2 = ((const float4*)bs)[64 + lane];
  v1.x = (v1.x - mean) * inv * g1.x + b1.x;
  v1.y = (v1.y - mean) * inv * g1.y + b1.y;
  v1.z = (v1.z - mean) * inv * g1.z + b1.z;
  v1.w = (v1.w - mean) * inv * g1.w + b1.w;
  v2.x = (v2.x - mean) * inv * g2.x + b2.x;
  v2.y = (v2.y - mean) * inv * g2.y + b2.y;
  v2.z = (v2.z - mean) * inv * g2.z + b2.z;
  v2.w = (v2.w - mean) * inv * g2.w + b2.w;
  ((float4*)p)[lane] = v1;
  ((float4*)p)[64 + lane] = v2;
}

// ---------------------------------------------------------------- launch
extern "C" void kernel_launch(void* const* d_in, const int* in_sizes, int n_in,
                              void* d_out, int out_size, void* d_ws, size_t ws_size,
                              hipStream_t stream) {
  const int*   tok   = (const int*)d_in[0];
  const float* emb_r = (const float*)d_in[1];
  const float* emb_i = (const float*)d_in[2];
  const float* Wr    = (const float*)d_in[3];
  const float* br    = (const float*)d_in[4];
  const float* Wu    = (const float*)d_in[5];
  const float* bu    = (const float*)d_in[6];
  const float* Wc    = (const float*)d_in[7];
  const float* bc    = (const float*)d_in[8];
  const float* lnrs  = (const float*)d_in[9];
  const float* lnrb  = (const float*)d_in[10];
  const float* lnis  = (const float*)d_in[11];
  const float* lnib  = (const float*)d_in[12];
  float* out = (float*)d_out;
  char* ws = (char*)d_ws;

  u16*   XS    = (u16*)(ws);                       //  33,554,432 B
  u16*   WT    = (u16*)(ws + 33554432);            //   6,291,456 B
  u16*   WTh   = (u16*)(ws + 39845888);            //   6,291,456 B (f16)
  u16*   XW    = (u16*)(ws + 46137344);            // 100,663,296 B
  u64*   hrec  = (u64*)(ws + 146800640);           //      32,768 B (8 isl x 512)
  u64*   rrec  = (u64*)(ws + 146833408);           //      32,768 B

  k_init<<<32, 256, 0, stream>>>(hrec);            // zeroes hrec + rrec (contiguous)
  k_prep<<<6144, 256, 0, stream>>>(Wr, Wu, Wc, WT, WTh);
  k_gather<<<8192, 256, 0, stream>>>(tok, emb_r, emb_i, XS);
  k_gemm<<<3072, 256, 0, stream>>>(XS, WT, XW);
  k_gru<<<256, 512, 0, stream>>>(WTh, br, bu, bc, XW, hrec, rrec, out);
  k_ln<<<8192, 256, 0, stream>>>(out, lnrs, lnrb, lnis, lnib);
}

// Round 12
// 6528.984 us; speedup vs baseline: 1.5334x; 1.3423x over previous
//
#include <hip/hip_runtime.h>
#include <hip/hip_bf16.h>

#define B_   8
#define T_   2048
#define OUT1_OFF 8388608ull   // 8*2048*512

typedef unsigned short u16;
typedef unsigned int   u32;
typedef unsigned long long u64;
typedef __attribute__((ext_vector_type(2))) _Float16 f16x2;

__device__ __forceinline__ u16 f2bf(float f) {
  u32 u = __builtin_bit_cast(u32, f);
  u32 r = (u + 0x7fffu + ((u >> 16) & 1u)) >> 16;   // RNE
  return (u16)r;
}
__device__ __forceinline__ float bf2f(u16 s) {
  u32 u = ((u32)s) << 16;
  return __builtin_bit_cast(float, u);
}
__device__ __forceinline__ u16 f2h(float f) {
  _Float16 h = (_Float16)f;                          // RNE cvt
  return __builtin_bit_cast(u16, h);
}
__device__ __forceinline__ u64 ald64(const u64* p) {
  return __hip_atomic_load(p, __ATOMIC_RELAXED, __HIP_MEMORY_SCOPE_AGENT);
}
__device__ __forceinline__ void ast64(u64* p, u64 v) {
  __hip_atomic_store(p, v, __ATOMIC_RELAXED, __HIP_MEMORY_SCOPE_AGENT);
}
// 2xf16 dot with f32 accumulate (v_dot2_f32_f16), safe fallback
__device__ __forceinline__ float dot2(u32 w, u32 h, float c) {
#if defined(__has_builtin) && __has_builtin(__builtin_amdgcn_fdot2)
  return __builtin_amdgcn_fdot2(__builtin_bit_cast(f16x2, w),
                                __builtin_bit_cast(f16x2, h), c, false);
#else
  f16x2 a = __builtin_bit_cast(f16x2, w), b = __builtin_bit_cast(f16x2, h);
  return c + (float)a.x * (float)b.x + (float)a.y * (float)b.y;
#endif
}

// ---------------------------------------------------------------- init
__global__ void k_init(u64* recs) {
  int i = blockIdx.x * 256 + threadIdx.x;   // 8192 u64 (hrec 4096 + rrec 4096)
  __hip_atomic_store(&recs[i], 0ull, __ATOMIC_RELAXED, __HIP_MEMORY_SCOPE_AGENT);
}

// ---------------------------------------------------------------- weight prep
// WT  (bf16) [3072][1024]: x-part transpose  WT [g*1024+j][k] = W_g[k][j]
// WTh (f16)  [3072][1024]: h-part transpose  WTh[g*1024+j][k] = W_g[1024+k][j]
__global__ __launch_bounds__(256) void k_prep(const float* __restrict__ Wr,
                                              const float* __restrict__ Wu,
                                              const float* __restrict__ Wc,
                                              u16* __restrict__ WT,
                                              u16* __restrict__ WTh) {
  __shared__ float tile[32][33];
  int bid = blockIdx.x;
  int g = bid >> 11;          // 0..2
  int rest = bid & 2047;
  int kt = rest >> 5;         // 0..63  (row tile over 2048)
  int jt = rest & 31;         // 0..31  (col tile over 1024)
  const float* W = (g == 0) ? Wr : ((g == 1) ? Wu : Wc);
  int tid = threadIdx.x;
  int r = tid >> 3, c4 = (tid & 7) * 4;
  const float4 v = *(const float4*)&W[(size_t)(kt * 32 + r) * 1024 + jt * 32 + c4];
  tile[r][c4 + 0] = v.x; tile[r][c4 + 1] = v.y;
  tile[r][c4 + 2] = v.z; tile[r][c4 + 3] = v.w;
  __syncthreads();
  int n = g * 1024 + jt * 32 + r;
  if (kt < 32) {
    int k = kt * 32 + c4;
    ushort4 o;
    o.x = f2bf(tile[c4 + 0][r]); o.y = f2bf(tile[c4 + 1][r]);
    o.z = f2bf(tile[c4 + 2][r]); o.w = f2bf(tile[c4 + 3][r]);
    *(ushort4*)&WT[(size_t)n * 1024 + k] = o;
  } else {
    int k = (kt - 32) * 32 + c4;
    ushort4 o;
    o.x = f2h(tile[c4 + 0][r]); o.y = f2h(tile[c4 + 1][r]);
    o.z = f2h(tile[c4 + 2][r]); o.w = f2h(tile[c4 + 3][r]);
    *(ushort4*)&WTh[(size_t)n * 1024 + k] = o;
  }
}

// ---------------------------------------------------------------- embedding gather -> bf16
__global__ __launch_bounds__(256) void k_gather(const int* __restrict__ tok,
                                                const float* __restrict__ er,
                                                const float* __restrict__ ei,
                                                u16* __restrict__ XS) {
  int row = blockIdx.x * 2 + (threadIdx.x >> 7);  // 0..16383 = b*T+t
  int lt = threadIdx.x & 127;
  int tk = tok[row];
  int c0 = lt * 8;
  const float* p = (c0 < 512) ? (er + (size_t)tk * 512 + c0)
                              : (ei + (size_t)tk * 512 + (c0 - 512));
  float4 v1 = *(const float4*)p;
  float4 v2 = *(const float4*)(p + 4);
  uint4 o;
  o.x = (u32)f2bf(v1.x) | ((u32)f2bf(v1.y) << 16);
  o.y = (u32)f2bf(v1.z) | ((u32)f2bf(v1.w) << 16);
  o.z = (u32)f2bf(v2.x) | ((u32)f2bf(v2.y) << 16);
  o.w = (u32)f2bf(v2.z) | ((u32)f2bf(v2.w) << 16);
  *(uint4*)&XS[(size_t)row * 1024 + c0] = o;
}

// ---------------------------------------------------------------- bf16 MFMA GEMM: XW = XS @ W_top
typedef __attribute__((ext_vector_type(8))) __bf16 bf16x8;
typedef __attribute__((ext_vector_type(4))) float f32x4;

__device__ __forceinline__ void gload16(const void* g, void* l) {
  __builtin_amdgcn_global_load_lds((const __attribute__((address_space(1))) void*)g,
                                   (__attribute__((address_space(3))) void*)l, 16, 0, 0);
}

__global__ __launch_bounds__(256) void k_gemm(const u16* __restrict__ XS,
                                              const u16* __restrict__ WT,
                                              u16* __restrict__ XW) {
  __shared__ u16 As[128 * 32];
  __shared__ u16 Bs[128 * 32];
  int bid = blockIdx.x;
  int m0 = (bid & 127) * 128;   // 128 m-tiles
  int n0 = (bid >> 7) * 128;    // 24 n-tiles
  int tid = threadIdx.x;
  int wave = tid >> 6, lane = tid & 63;
  int wm = wave >> 1, wn = wave & 1;
  f32x4 acc[4][4] = {};
  int lr = lane & 15, lk = (lane >> 4) * 8;
  int srow = lane >> 2, sc8 = (lane & 3) * 8;
  for (int k0 = 0; k0 < 1024; k0 += 32) {
#pragma unroll
    for (int q = 0; q < 2; ++q) {
      int rbase = wave * 32 + q * 16;
      gload16(XS + (size_t)(m0 + rbase + srow) * 1024 + k0 + sc8, &As[rbase * 32]);
      gload16(WT + (size_t)(n0 + rbase + srow) * 1024 + k0 + sc8, &Bs[rbase * 32]);
    }
    __syncthreads();
    bf16x8 a[4], b[4];
#pragma unroll
    for (int mi = 0; mi < 4; ++mi) a[mi] = *(const bf16x8*)&As[(wm * 64 + mi * 16 + lr) * 32 + lk];
#pragma unroll
    for (int ni = 0; ni < 4; ++ni) b[ni] = *(const bf16x8*)&Bs[(wn * 64 + ni * 16 + lr) * 32 + lk];
#pragma unroll
    for (int mi = 0; mi < 4; ++mi)
#pragma unroll
      for (int ni = 0; ni < 4; ++ni)
        acc[mi][ni] = __builtin_amdgcn_mfma_f32_16x16x32_bf16(a[mi], b[ni], acc[mi][ni], 0, 0, 0);
    __syncthreads();
  }
#pragma unroll
  for (int mi = 0; mi < 4; ++mi)
#pragma unroll
    for (int ni = 0; ni < 4; ++ni) {
      int col = n0 + wn * 64 + ni * 16 + lr;
#pragma unroll
      for (int r = 0; r < 4; ++r) {
        int row = m0 + wm * 64 + mi * 16 + (lane >> 4) * 4 + r;
        XW[(size_t)row * 3072 + col] = f2bf(acc[mi][ni][r]);
      }
    }
}

// ---------------------------------------------------------------- wave fold-reduce
// p[N] per lane; returns full-wave dot for index (lane & (N-1)), replicated.
template <int N>
__device__ __forceinline__ float foldreduce(float (&p)[N], int lane) {
#pragma unroll
  for (int s = 0; (1 << s) < N; ++s) {
    const int m = 1 << s;
    const int bit = (lane >> s) & 1;
#pragma unroll
    for (int i = 0; i < (N >> (s + 1)); ++i) {
      float lo = p[2 * i], hi = p[2 * i + 1];
      float mine = bit ? hi : lo;
      float send = bit ? lo : hi;
      p[i] = mine + __shfl_xor(send, m, 64);
    }
  }
  float v = p[0];
#pragma unroll
  for (int s = 0; s < 6; ++s)
    if ((1 << s) >= N) v += __shfl_xor(v, 1 << s, 64);
  return v;
}

// ---------------------------------------------------------------- persistent GRU
// R9 structure EXACTLY (8 islands x 32 WGs x 512 thr; wave w owns phase-A
// slots p=w*8+i (waves 0-3 r-gate, 4-7 u-gate), phase-B cols w*4+i; u_l /
// hown_l in LDS; 4 syncthreads; tagged u64 records {tag32 | 2 packed vals}).
// Single change vs R9: values/weights are f16, matvec uses v_dot2_f32_f16.
// Record q covers adjacent cols (2q, 2q+1); weight u32 [64*j2+L] covers the
// same adjacent-k pair -> one dot2 per pair.
__global__ __launch_bounds__(512, 1) void k_gru(const u16* __restrict__ WTh,
                                                const float* __restrict__ br,
                                                const float* __restrict__ bu,
                                                const float* __restrict__ bc,
                                                const u16* __restrict__ XW,
                                                u64* __restrict__ hrec,
                                                u64* __restrict__ rrec,
                                                float* __restrict__ out) {
  __shared__ u32 pk[512];          // staging (h payload, then reused for rh)
  __shared__ float u_l[32];
  __shared__ float hown_l[32];     // fp32-exact own-col h state

  const int tid = threadIdx.x;
  const int L = tid & 63;
  const int w = tid >> 6;
  const int isl = blockIdx.x >> 5;      // island = batch
  const int wg = blockIdx.x & 31;
  const int j0 = wg * 32;

  // ---- weights into VGPRs (f16 adjacent-pair u32 loads, coalesced)
  // phase A slot p = w*8+i: gate p>>5 (0=r,1=u), col j0 + (p&31)
  u32 wA[8][8];
#pragma unroll
  for (int i = 0; i < 8; ++i) {
    int p = w * 8 + i;
    const u32* wr = (const u32*)(WTh + (size_t)((p >> 5) * 1024 + j0 + (p & 31)) * 1024);
#pragma unroll
    for (int j2 = 0; j2 < 8; ++j2) wA[i][j2] = wr[64 * j2 + L];
  }
  u32 wB[4][8];
#pragma unroll
  for (int i = 0; i < 4; ++i) {
    const u32* wr = (const u32*)(WTh + (size_t)(2048 + j0 + w * 4 + i) * 1024);
#pragma unroll
    for (int j2 = 0; j2 < 8; ++j2) wB[i][j2] = wr[64 * j2 + L];
  }

  float biasA = 0.f, bcB = 0.f;
  if (L < 8) {
    int p = w * 8 + L;
    biasA = ((p >= 32) ? bu : br)[j0 + (p & 31)];
  }
  if (L < 4) bcB = bc[j0 + w * 4 + L];
  if (tid < 32) hown_l[tid] = 0.f;

  u64* hr = hrec + (size_t)isl * 512;   // record q covers cols {2q, 2q+1}
  u64* rr = rrec + (size_t)isl * 512;

  __syncthreads();

  for (int t = 0; t < T_; ++t) {
    const size_t xrow = ((size_t)isl * T_ + t) * 3072;
    // early xw loads (in flight during poll)
    float xwA = 0.f, xwB = 0.f;
    if (L < 8) {
      int p = w * 8 + L;
      xwA = bf2f(XW[xrow + (p >> 5) * 1024 + j0 + (p & 31)]);
    }
    if (L < 4) xwB = bf2f(XW[xrow + 2048 + j0 + w * 4 + L]);

    // ---- phase A: poll own h record (tag >= t), stage packed payload
    u64 hv = ald64(&hr[tid]);
    while ((u32)(hv >> 32) < (u32)t) hv = ald64(&hr[tid]);
    pk[tid] = (u32)hv;
    __syncthreads();

    u32 hq[8];
#pragma unroll
    for (int j2 = 0; j2 < 8; ++j2) hq[j2] = pk[64 * j2 + L];
    float acc[8];
#pragma unroll
    for (int i = 0; i < 8; ++i) {
      float a = 0.f;
#pragma unroll
      for (int j2 = 0; j2 < 8; ++j2) a = dot2(wA[i][j2], hq[j2], a);
      acc[i] = a;
    }
    float dA = foldreduce<8>(acc, L);
    float sg = 1.f / (1.f + __expf(-(dA + xwA + biasA)));
    // r-gate waves (w<4): produce rh, publish tagged adjacent pairs
    float rh = 0.f;
    if (L < 8 && w < 4) rh = sg * hown_l[w * 8 + L];
    float rhp = __shfl_xor(rh, 1, 64);
    if (w < 4 && L < 8 && (L & 1) == 0) {
      int p = w * 8 + L;
      u64 x = ((u64)(u32)(t + 1) << 32) |
              (u64)((u32)f2h(rh) | ((u32)f2h(rhp) << 16));
      ast64(&rr[(j0 + p) >> 1], x);
    }
    if (L < 8 && w >= 4) u_l[w * 8 + L - 32] = sg;
    __syncthreads();   // u_l visible; pk reads complete before rh staging

    // ---- phase B: poll own rh record (tag >= t+1), stage
    u64 rv = ald64(&rr[tid]);
    while ((u32)(rv >> 32) < (u32)(t + 1)) rv = ald64(&rr[tid]);
    pk[tid] = (u32)rv;
    __syncthreads();

    u32 rq[8];
#pragma unroll
    for (int j2 = 0; j2 < 8; ++j2) rq[j2] = pk[64 * j2 + L];
    float accB[4];
#pragma unroll
    for (int i = 0; i < 4; ++i) {
      float a = 0.f;
#pragma unroll
      for (int j2 = 0; j2 < 8; ++j2) a = dot2(wB[i][j2], rq[j2], a);
      accB[i] = a;
    }
    float dB = foldreduce<4>(accB, L);
    float hn = 0.f;
    if (L < 4) {
      int c = w * 4 + L;
      float pre = dB + xwB + bcB;
      float ax = fabsf(pre);
      float e = __expf(-2.f * ax);
      float cv = copysignf((1.f - e) / (1.f + e), pre);
      float uu = u_l[c];
      hn = (1.f - uu) * hown_l[c] + uu * cv;
      hown_l[c] = hn;
      int j = j0 + c;
      size_t orow = (size_t)isl * T_ + t;
      if (j < 512) out[orow * 512 + j] = hn;
      else out[OUT1_OFF + orow * 512 + (j - 512)] = hn;
    }
    // publish tagged h pairs: lanes 0,2 (cols w*4+{0,1} / w*4+{2,3})
    float hp = __shfl_xor(hn, 1, 64);
    if (L < 4 && (L & 1) == 0) {
      int j = j0 + w * 4 + L;
      u64 x = ((u64)(u32)(t + 1) << 32) |
              (u64)((u32)f2h(hn) | ((u32)f2h(hp) << 16));
      ast64(&hr[j >> 1], x);
    }
    __syncthreads();   // hown_l/pk settled before next iteration
  }
}

// ---------------------------------------------------------------- in-place LayerNorm
__global__ __launch_bounds__(256) void k_ln(float* __restrict__ out,
                                            const float* __restrict__ sr,
                                            const float* __restrict__ brr,
                                            const float* __restrict__ si,
                                            const float* __restrict__ bii) {
  int row = blockIdx.x * 4 + (threadIdx.x >> 6);   // 0..32767
  int lane = threadIdx.x & 63;
  float* p = out + (size_t)row * 512;
  float4 v1 = ((const float4*)p)[lane];
  float4 v2 = ((const float4*)p)[64 + lane];
  float s1 = v1.x + v1.y + v1.z + v1.w + v2.x + v2.y + v2.z + v2.w;
  float s2 = v1.x * v1.x + v1.y * v1.y + v1.z * v1.z + v1.w * v1.w +
             v2.x * v2.x + v2.y * v2.y + v2.z * v2.z + v2.w * v2.w;
#pragma unroll
  for (int m = 1; m < 64; m <<= 1) { s1 += __shfl_xor(s1, m, 64); s2 += __shfl_xor(s2, m, 64); }
  float mean = s1 * (1.f / 512.f);
  float var = s2 * (1.f / 512.f) - mean * mean;
  float inv = rsqrtf(var + 1e-6f);
  bool hi2 = row >= 16384;
  const float* sc = hi2 ? si : sr;
  const float* bs = hi2 ? bii : brr;
  float4 g1 = ((const float4*)sc)[lane], g2 = ((const float4*)sc)[64 + lane];
  float4 b1 = ((const float4*)bs)[lane], b2 = ((const float4*)bs)[64 + lane];
  v1.x = (v1.x - mean) * inv * g1.x + b1.x;
  v1.y = (v1.y - mean) * inv * g1.y + b1.y;
  v1.z = (v1.z - mean) * inv * g1.z + b1.z;
  v1.w = (v1.w - mean) * inv * g1.w + b1.w;
  v2.x = (v2.x - mean) * inv * g2.x + b2.x;
  v2.y = (v2.y - mean) * inv * g2.y + b2.y;
  v2.z = (v2.z - mean) * inv * g2.z + b2.z;
  v2.w = (v2.w - mean) * inv * g2.w + b2.w;
  ((float4*)p)[lane] = v1;
  ((float4*)p)[64 + lane] = v2;
}

// ---------------------------------------------------------------- launch
extern "C" void kernel_launch(void* const* d_in, const int* in_sizes, int n_in,
                              void* d_out, int out_size, void* d_ws, size_t ws_size,
                              hipStream_t stream) {
  const int*   tok   = (const int*)d_in[0];
  const float* emb_r = (const float*)d_in[1];
  const float* emb_i = (const float*)d_in[2];
  const float* Wr    = (const float*)d_in[3];
  const float* br    = (const float*)d_in[4];
  const float* Wu    = (const float*)d_in[5];
  const float* bu    = (const float*)d_in[6];
  const float* Wc    = (const float*)d_in[7];
  const float* bc    = (const float*)d_in[8];
  const float* lnrs  = (const float*)d_in[9];
  const float* lnrb  = (const float*)d_in[10];
  const float* lnis  = (const float*)d_in[11];
  const float* lnib  = (const float*)d_in[12];
  float* out = (float*)d_out;
  char* ws = (char*)d_ws;

  u16*   XS    = (u16*)(ws);                       //  33,554,432 B
  u16*   WT    = (u16*)(ws + 33554432);            //   6,291,456 B
  u16*   WTh   = (u16*)(ws + 39845888);            //   6,291,456 B (f16)
  u16*   XW    = (u16*)(ws + 46137344);            // 100,663,296 B
  u64*   hrec  = (u64*)(ws + 146800640);           //      32,768 B (8 isl x 512)
  u64*   rrec  = (u64*)(ws + 146833408);           //      32,768 B

  k_init<<<32, 256, 0, stream>>>(hrec);            // zeroes hrec + rrec (contiguous)
  k_prep<<<6144, 256, 0, stream>>>(Wr, Wu, Wc, WT, WTh);
  k_gather<<<8192, 256, 0, stream>>>(tok, emb_r, emb_i, XS);
  k_gemm<<<3072, 256, 0, stream>>>(XS, WT, XW);
  k_gru<<<256, 512, 0, stream>>>(WTh, br, bu, bc, XW, hrec, rrec, out);
  k_ln<<<8192, 256, 0, stream>>>(out, lnrs, lnrb, lnis, lnib);
}